// Round 3
// baseline (213.182 us; speedup 1.0000x reference)
//
#include <hip/hip_runtime.h>
#include <stdint.h>

typedef int   int32x4   __attribute__((ext_vector_type(4)));
typedef int   int32x16  __attribute__((ext_vector_type(16)));
typedef float floatx4   __attribute__((ext_vector_type(4)));

#define B_ROWS 131072
#define DK 512           // K (= D)
#define FN 512           // N (= F)
#define BM 64            // rows per block (32 KB LDS)
#define A_SCALE_F ((float)(127.0 / 6.0))

// ---------------- prepass: quantize weights into B-fragment layout -------------
// 32 blocks x 256 threads; block handles 16 columns, 16 row-groups of 32 rows.
// wq layout: [FN][DK] int8, k-contiguous -> MFMA B fragment = straight 16B load.
// Also emits inv_cs[n] = 1/(a_scale*w_scale[n]) (double-precision reciprocal).
__global__ void wq_quant_kernel(const float* __restrict__ kern,  // [DK][FN]
                                int8_t* __restrict__ wq,         // [FN][DK]
                                float* __restrict__ invcs) {     // [FN]
  __shared__ float smax[256];
  __shared__ float sscale[16];
  const int c = threadIdx.x & 15;        // col within block
  const int g = threadIdx.x >> 4;        // row-group 0..15 (32 rows each)
  const int col = blockIdx.x * 16 + c;

  float m = 0.f;
#pragma unroll 8
  for (int i = 0; i < 32; ++i) {
    m = fmaxf(m, fabsf(kern[(size_t)(g * 32 + i) * FN + col]));
  }
  smax[threadIdx.x] = m;
  __syncthreads();
  if (threadIdx.x < 16) {
    float mm = smax[threadIdx.x];
#pragma unroll
    for (int g2 = 1; g2 < 16; ++g2) mm = fmaxf(mm, smax[g2 * 16 + threadIdx.x]);
    const float wb = fmaxf(mm, 1e-6f);
    const float ws = 127.f / wb;               // f32 divide, matches jnp w_scale
    sscale[threadIdx.x] = ws;
    // combined dequant scale, inverted in double for accuracy (mul in epilogue)
    invcs[blockIdx.x * 16 + threadIdx.x] =
        (float)(1.0 / ((double)A_SCALE_F * (double)ws));
  }
  __syncthreads();
  const float ws = sscale[c];
  uint32_t* wq32 = (uint32_t*)(wq + (size_t)col * DK);
#pragma unroll
  for (int d4 = 0; d4 < 8; ++d4) {             // 32 rows -> 8 packed words
    uint32_t p = 0;
#pragma unroll
    for (int j = 0; j < 4; ++j) {
      float v = kern[(size_t)(g * 32 + d4 * 4 + j) * FN + col] * ws;
      v = floorf(v + 0.5f);                    // AQT round: floor(v+0.5)
      v = fminf(fmaxf(v, -127.f), 127.f);
      p |= ((uint32_t)((int)v & 255)) << (8 * j);
    }
    wq32[g * 8 + d4] = p;
  }
}

// ---------------- main GEMM ----------------------------------------------------
// 2048 blocks x 512 threads (8 waves: 2 in M x 4 in N).
// Wave owns 32 rows x 128 cols via mfma_i32_32x32x32_i8 (acc = 64 AGPRs).
// LDS: 64x512 int8 x-tile, full 32-slot XOR swizzle for conflict-free b128 reads.
// Epilogue stores are 2x128B full lines per instruction (no partial-line RMW).
__global__ __launch_bounds__(512, 4)
void aqt_gemm_kernel(const float* __restrict__ x,     // [B_ROWS][DK]
                     const int8_t* __restrict__ wq,   // [FN][DK]
                     const float* __restrict__ invcs, // [FN]
                     const float* __restrict__ bias,  // [FN]
                     float* __restrict__ out) {       // [B_ROWS][FN]
  __shared__ __align__(16) char xq[BM * DK];          // 32 KB

  const int tid  = threadIdx.x;
  const int lane = tid & 63;
  const int wv   = tid >> 6;        // 0..7
  const int wM   = wv >> 2;         // 0..1 -> 32-row strip
  const int wN   = wv & 3;          // 0..3 -> 128-col strip
  const int l31  = lane & 31;
  const int l5   = lane >> 5;       // k-half

  const size_t mBase = (size_t)blockIdx.x * BM;
  const float* xg = x + mBase * DK;

  // ---- stage: quantize x tile (fp32 -> int8) into swizzled LDS ----
  {
    const int c4 = tid & 127;       // float4 index within a row
    const int r0 = tid >> 7;        // 0..3
    floatx4 v[16];
#pragma unroll
    for (int i = 0; i < 16; ++i) {  // 16 loads in flight (256B/thread)
      const int r = i * 4 + r0;
      v[i] = *(const floatx4*)(xg + (size_t)r * DK + c4 * 4);
    }
#pragma unroll
    for (int i = 0; i < 16; ++i) {
      const int r = i * 4 + r0;
      uint32_t p = 0;
#pragma unroll
      for (int j = 0; j < 4; ++j) {
        float q = floorf(v[i][j] * A_SCALE_F + 0.5f);   // AQT round
        q = fminf(fmaxf(q, -127.f), 127.f);
        p |= ((uint32_t)((int)q & 255)) << (8 * j);
      }
      *(uint32_t*)(&xq[r * DK + ((c4 * 4) ^ ((r & 31) << 4))]) = p;
    }
  }
  __syncthreads();

  // ---- K loop: 16 steps of K=32; wave computes 32x128 via 4 fragments ----
  int32x16 acc[4];
#pragma unroll
  for (int n = 0; n < 4; ++n) acc[n] = (int32x16)(0);

  const int arow = wM * 32 + l31;                  // A fragment row (in tile)
  const char* aBase = &xq[arow * DK];
  const int aSwz = (arow & 31) << 4;

#pragma unroll
  for (int ks = 0; ks < 16; ++ks) {
    const int kb = ks * 32 + l5 * 16;              // k byte offset
    int32x4 a = *(const int32x4*)(aBase + (kb ^ aSwz));
    int32x4 b[4];
#pragma unroll
    for (int n = 0; n < 4; ++n) {
      const int col = wN * 128 + n * 32 + l31;     // B fragment col
      b[n] = *(const int32x4*)(wq + (size_t)col * DK + kb);
    }
#pragma unroll
    for (int n = 0; n < 4; ++n)
      acc[n] = __builtin_amdgcn_mfma_i32_32x32x32_i8(a, b[n], acc[n], 0, 0, 0);
  }

  // ---- epilogue: dequant (mul by inverse combined scale) + bias ----
#pragma unroll
  for (int n = 0; n < 4; ++n) {
    const int col = wN * 128 + n * 32 + l31;
    const float inv = invcs[col];
    const float bv  = bias[col];
#pragma unroll
    for (int r = 0; r < 16; ++r) {
      const int rowl = (r & 3) + 8 * (r >> 2) + 4 * l5;   // 32x32 C/D row map
      const size_t row = mBase + (size_t)(wM * 32 + rowl);
      out[row * FN + col] = (float)acc[n][r] * inv + bv;  // 2x128B lines/store
    }
  }
}

extern "C" void kernel_launch(void* const* d_in, const int* in_sizes, int n_in,
                              void* d_out, int out_size, void* d_ws, size_t ws_size,
                              hipStream_t stream) {
  const float* x    = (const float*)d_in[0];
  const float* kern = (const float*)d_in[1];
  const float* bias = (const float*)d_in[2];
  // d_in[3] = padding_mask: with fixed act bounds + eval mode it does not enter the math.

  int8_t* wq    = (int8_t*)d_ws;                           // 256 KB
  float*  invcs = (float*)((char*)d_ws + (size_t)FN * DK); // 2 KB

  wq_quant_kernel<<<32, 256, 0, stream>>>(kern, wq, invcs);
  aqt_gemm_kernel<<<B_ROWS / BM, 512, 0, stream>>>(x, wq, invcs, bias, (float*)d_out);
}